// Round 2
// baseline (24644.112 us; speedup 1.0000x reference)
//
#include <hip/hip_runtime.h>
#include <stdint.h>
#include <stddef.h>

#define B_ 64
#define T_ 128
#define S_ 128
#define H_ 1024
#define E_ 512
#define V_ 4000
#define VP_ 4032
#define XH_ 1536
#define BH_ (B_*H_)

typedef __attribute__((ext_vector_type(8))) short bf16x8;
typedef __attribute__((ext_vector_type(4))) float f32x4;
typedef unsigned short u16;

__device__ __forceinline__ float bf2f(u16 x){
  union { unsigned int u; float f; } c; c.u = ((unsigned int)x) << 16; return c.f;
}
__device__ __forceinline__ u16 f2bf(float f){
  union { float f; unsigned int u; } c; c.f = f;
  return (u16)((c.u + 0x7FFFu + ((c.u >> 16) & 1u)) >> 16);
}
__device__ __forceinline__ void split2(float x, u16& hi, u16& lo){
  u16 h = f2bf(x); hi = h; lo = f2bf(x - bf2f(h));
}
__device__ __forceinline__ float sigm(float x){ return 1.f/(1.f+__expf(-x)); }
__device__ __forceinline__ float tanh_f(float x){
  float z = __expf(-2.f*fabsf(x));
  float r = (1.f - z)/(1.f + z);
  return x < 0.f ? -r : r;
}

// ---------------- prep kernels ----------------

__global__ __launch_bounds__(256) void k_f2bf(const float* __restrict__ in, u16* __restrict__ out, int n){
  int i = blockIdx.x*256 + threadIdx.x;
  if (i < n) out[i] = f2bf(in[i]);
}

__global__ __launch_bounds__(256) void k_split(const float* __restrict__ in,
                                               u16* __restrict__ hi, u16* __restrict__ lo, int n){
  int i = blockIdx.x*256 + threadIdx.x;
  if (i < n){ u16 a, b; split2(in[i], a, b); hi[i] = a; lo[i] = b; }
}

__global__ __launch_bounds__(256) void k_waT_split(const float* __restrict__ Wa,
                                                   u16* __restrict__ Th, u16* __restrict__ Tl){
  // T[n][h] = Wa[h][n], split hi/lo
  int n = blockIdx.x;
  for (int h = threadIdx.x; h < H_; h += 256){
    u16 a, b; split2(Wa[(size_t)h*H_ + n], a, b);
    Th[(size_t)n*H_ + h] = a; Tl[(size_t)n*H_ + h] = b;
  }
}

__global__ __launch_bounds__(256) void k_bias(const float* __restrict__ a, const float* __restrict__ b,
                                              float* __restrict__ o, int n){
  int i = blockIdx.x*256 + threadIdx.x;
  if (i < n) o[i] = a[i] + b[i];
}

__global__ __launch_bounds__(256) void k_emb(const int* __restrict__ tok, const float* __restrict__ emb,
                                             u16* __restrict__ ehi, u16* __restrict__ elo){
  // e layout [t][b][j]; grid = T_*B_ blocks, bid = t*64 + b
  int bid = blockIdx.x;
  int t = bid >> 6, b = bid & 63;
  int tk = tok[b*T_ + t];
  const float* src = emb + (size_t)tk*E_;
  u16* dh = ehi + (size_t)bid*E_;
  u16* dl = elo + (size_t)bid*E_;
  for (int j = threadIdx.x; j < E_; j += 256){
    if (tk == 0){ dh[j] = 0; dl[j] = 0; }
    else { u16 a, c; split2(src[j], a, c); dh[j] = a; dl[j] = c; }
  }
}

__global__ __launch_bounds__(256) void k_init(const float* __restrict__ h0, const float* __restrict__ c0,
                                              float* __restrict__ hs, float* __restrict__ cs,
                                              u16* __restrict__ h0h, u16* __restrict__ h0l,
                                              u16* __restrict__ h1h, u16* __restrict__ h1l){
  int i = blockIdx.x*256 + threadIdx.x;
  if (i < 2*BH_){ hs[i] = h0[i]; cs[i] = c0[i]; }
  if (i < BH_){
    u16 a, b;
    split2(h0[i], a, b);        h0h[i] = a; h0l[i] = b;
    split2(h0[BH_ + i], a, b);  h1h[i] = a; h1l[i] = b;
  }
}

// encWa[r][n] = sum_h enc[r][h] * Wa[h][n]  (fp32 out via 3-pass hi/lo MFMA)
__global__ __launch_bounds__(256) void k_encWa(const u16* __restrict__ Ah, const u16* __restrict__ Al,
                                               const u16* __restrict__ Bh, const u16* __restrict__ Bl,
                                               float* __restrict__ out){
  int w = threadIdx.x >> 6, lane = threadIdx.x & 63;
  int lm = lane & 15, q = lane >> 4, qo = q*8;
  int m0 = blockIdx.x*64 + w*16;
  int n0 = blockIdx.y*64;
  const u16* arh = Ah + (size_t)(m0 + lm)*H_ + qo;
  const u16* arl = Al + (size_t)(m0 + lm)*H_ + qo;
  const u16* brh[4]; const u16* brl[4];
  #pragma unroll
  for (int nf = 0; nf < 4; nf++){
    brh[nf] = Bh + (size_t)(n0 + nf*16 + lm)*H_ + qo;
    brl[nf] = Bl + (size_t)(n0 + nf*16 + lm)*H_ + qo;
  }
  f32x4 acc[4] = {};
  for (int k = 0; k < H_; k += 32){
    bf16x8 ah = *(const bf16x8*)(arh + k);
    bf16x8 al = *(const bf16x8*)(arl + k);
    #pragma unroll
    for (int nf = 0; nf < 4; nf++){
      bf16x8 bh = *(const bf16x8*)(brh[nf] + k);
      bf16x8 bl = *(const bf16x8*)(brl[nf] + k);
      acc[nf] = __builtin_amdgcn_mfma_f32_16x16x32_bf16(ah, bh, acc[nf], 0, 0, 0);
      acc[nf] = __builtin_amdgcn_mfma_f32_16x16x32_bf16(al, bh, acc[nf], 0, 0, 0);
      acc[nf] = __builtin_amdgcn_mfma_f32_16x16x32_bf16(ah, bl, acc[nf], 0, 0, 0);
    }
  }
  #pragma unroll
  for (int nf = 0; nf < 4; nf++)
    #pragma unroll
    for (int r = 0; r < 4; r++)
      out[(size_t)(m0 + q*4 + r)*H_ + n0 + nf*16 + lm] = acc[nf][r];
}

// ---------------- per-step kernels ----------------

// attention (all fp32): scores[s] = h1[b] . encWa[b][s]; softmax; ctx = attn @ enc[b]
__global__ __launch_bounds__(256) void k_attn(const float* __restrict__ h1st, const float* __restrict__ encWa,
                                              const float* __restrict__ enc,
                                              u16* __restrict__ ctxh, u16* __restrict__ ctxl){
  int b = blockIdx.x;
  int tid = threadIdx.x, lane = tid & 63, w = tid >> 6;
  __shared__ float sm[S_], pr[S_];
  const float* h1r = h1st + (size_t)b*H_ + lane*16;
  float hf[16];
  #pragma unroll
  for (int j = 0; j < 16; j += 4){
    float4 v = *(const float4*)(h1r + j);
    hf[j] = v.x; hf[j+1] = v.y; hf[j+2] = v.z; hf[j+3] = v.w;
  }
  for (int s = w; s < S_; s += 4){
    const float* er = encWa + ((size_t)b*S_ + s)*H_ + lane*16;
    float acc = 0.f;
    #pragma unroll
    for (int j = 0; j < 16; j += 4){
      float4 v = *(const float4*)(er + j);
      acc += hf[j]*v.x + hf[j+1]*v.y + hf[j+2]*v.z + hf[j+3]*v.w;
    }
    #pragma unroll
    for (int off = 32; off; off >>= 1) acc += __shfl_xor(acc, off, 64);
    if (lane == 0) sm[s] = acc;
  }
  __syncthreads();
  float mx = -1e30f;
  for (int s = 0; s < S_; s++) mx = fmaxf(mx, sm[s]);
  if (tid < S_) pr[tid] = __expf(sm[tid] - mx);
  __syncthreads();
  float sum = 0.f;
  for (int s = 0; s < S_; s++) sum += pr[s];
  float inv = 1.f/sum;
  const float* eb = enc + (size_t)b*S_*H_ + tid*4;
  float c0 = 0.f, c1 = 0.f, c2 = 0.f, c3 = 0.f;
  for (int s = 0; s < S_; s++){
    float a = pr[s];
    float4 ev = *(const float4*)(eb + (size_t)s*H_);
    c0 += a*ev.x; c1 += a*ev.y; c2 += a*ev.z; c3 += a*ev.w;
  }
  int o = b*H_ + tid*4;
  u16 hh, hl;
  split2(c0*inv, hh, hl); ctxh[o]   = hh; ctxl[o]   = hl;
  split2(c1*inv, hh, hl); ctxh[o+1] = hh; ctxl[o+1] = hl;
  split2(c2*inv, hh, hl); ctxh[o+2] = hh; ctxl[o+2] = hl;
  split2(c3*inv, hh, hl); ctxh[o+3] = hh; ctxl[o+3] = hl;
}

__device__ __forceinline__ void gemm_hl(const u16* __restrict__ xh, const u16* __restrict__ xl, int kx,
                                        const u16* __restrict__ wh, const u16* __restrict__ wl,
                                        int ar0, int ar1, int qo,
                                        f32x4& acc0, f32x4& acc1){
  const u16* a0h = xh + (size_t)ar0*kx + qo;
  const u16* a1h = xh + (size_t)ar1*kx + qo;
  const u16* a0l = xl + (size_t)ar0*kx + qo;
  const u16* a1l = xl + (size_t)ar1*kx + qo;
  const u16* bh = wh + qo;
  const u16* bl = wl + qo;
  #pragma unroll 2
  for (int k = 0; k < kx; k += 32){
    bf16x8 vbh = *(const bf16x8*)(bh + k);
    bf16x8 vbl = *(const bf16x8*)(bl + k);
    bf16x8 v0h = *(const bf16x8*)(a0h + k);
    bf16x8 v0l = *(const bf16x8*)(a0l + k);
    bf16x8 v1h = *(const bf16x8*)(a1h + k);
    bf16x8 v1l = *(const bf16x8*)(a1l + k);
    acc0 = __builtin_amdgcn_mfma_f32_16x16x32_bf16(v0h, vbh, acc0, 0, 0, 0);
    acc1 = __builtin_amdgcn_mfma_f32_16x16x32_bf16(v1h, vbh, acc1, 0, 0, 0);
    acc0 = __builtin_amdgcn_mfma_f32_16x16x32_bf16(v0l, vbh, acc0, 0, 0, 0);
    acc1 = __builtin_amdgcn_mfma_f32_16x16x32_bf16(v1l, vbh, acc1, 0, 0, 0);
    acc0 = __builtin_amdgcn_mfma_f32_16x16x32_bf16(v0h, vbl, acc0, 0, 0, 0);
    acc1 = __builtin_amdgcn_mfma_f32_16x16x32_bf16(v1h, vbl, acc1, 0, 0, 0);
  }
}

// one LSTM cell, fp32-accurate via hi/lo. grid 128: blockIdx = j(0..63) | mh<<6.
__global__ __launch_bounds__(256) void k_lstm(
    const u16* __restrict__ x1h, const u16* __restrict__ x1l,
    const u16* __restrict__ W1h, const u16* __restrict__ W1l, int ld1, int k1,
    const u16* __restrict__ x2h, const u16* __restrict__ x2l,
    const u16* __restrict__ W2h, const u16* __restrict__ W2l, int ld2, int k2,
    const u16* __restrict__ x3h, const u16* __restrict__ x3l,
    const u16* __restrict__ W3h, const u16* __restrict__ W3l, int ld3, int k3,
    const float* __restrict__ bias,
    float* __restrict__ cst, float* __restrict__ hst,
    u16* __restrict__ hnh, u16* __restrict__ hnl, u16* __restrict__ hall){
  int j = blockIdx.x & 63, mh = blockIdx.x >> 6;
  int g = threadIdx.x >> 6;
  int lane = threadIdx.x & 63, lm = lane & 15, q = lane >> 4, qo = q*8;
  int n = g*H_ + j*16 + lm;
  int ar0 = mh*32 + lm, ar1 = mh*32 + 16 + lm;
  f32x4 acc0 = {}, acc1 = {};
  gemm_hl(x1h, x1l, k1, W1h + (size_t)n*ld1, W1l + (size_t)n*ld1, ar0, ar1, qo, acc0, acc1);
  gemm_hl(x2h, x2l, k2, W2h + (size_t)n*ld2, W2l + (size_t)n*ld2, ar0, ar1, qo, acc0, acc1);
  if (x3h) gemm_hl(x3h, x3l, k3, W3h + (size_t)n*ld3, W3l + (size_t)n*ld3, ar0, ar1, qo, acc0, acc1);
  __shared__ float smg[4][32][16];
  float bv = bias[n];
  #pragma unroll
  for (int r = 0; r < 4; r++){
    smg[g][q*4 + r][lm]      = acc0[r] + bv;
    smg[g][16 + q*4 + r][lm] = acc1[r] + bv;
  }
  __syncthreads();
  #pragma unroll
  for (int p = threadIdx.x; p < 512; p += 256){
    int bb = p >> 4, dd = p & 15;
    float iv = smg[0][bb][dd], fv = smg[1][bb][dd];
    float gv = smg[2][bb][dd], ov = smg[3][bb][dd];
    int bg = mh*32 + bb;
    size_t idx = (size_t)bg*H_ + j*16 + dd;
    float cn = sigm(fv)*cst[idx] + sigm(iv)*tanh_f(gv);
    float hn = sigm(ov)*tanh_f(cn);
    cst[idx] = cn; hst[idx] = hn;
    u16 hh, hl; split2(hn, hh, hl);
    hnh[idx] = hh; hnl[idx] = hl;
    if (hall) hall[idx] = hh;
  }
}

// ---------------- final projection + state copy ----------------

__global__ __launch_bounds__(256) void k_proj(const u16* __restrict__ h1all, const u16* __restrict__ Wp,
                                              const float* __restrict__ pb, float* __restrict__ out){
  int w = threadIdx.x >> 6, lane = threadIdx.x & 63;
  int lm = lane & 15, q = lane >> 4, qo = q*8;
  int m0 = blockIdx.x*64 + w*16;
  int n0 = blockIdx.y*64;
  const u16* arow = h1all + (size_t)(m0 + lm)*H_ + qo;
  const u16* brow[4];
  #pragma unroll
  for (int nf = 0; nf < 4; nf++) brow[nf] = Wp + (size_t)(n0 + nf*16 + lm)*H_ + qo;
  f32x4 acc[4] = {};
  for (int k = 0; k < H_; k += 32){
    bf16x8 a = *(const bf16x8*)(arow + k);
    #pragma unroll
    for (int nf = 0; nf < 4; nf++){
      bf16x8 bb = *(const bf16x8*)(brow[nf] + k);
      acc[nf] = __builtin_amdgcn_mfma_f32_16x16x32_bf16(a, bb, acc[nf], 0, 0, 0);
    }
  }
  #pragma unroll
  for (int nf = 0; nf < 4; nf++){
    int v = n0 + nf*16 + lm;
    if (v >= V_) continue;
    float bias = pb[v];
    #pragma unroll
    for (int r = 0; r < 4; r++){
      int row = m0 + q*4 + r;           // row = t*64 + b
      int t = row >> 6, b = row & 63;
      out[((size_t)b*T_ + t)*V_ + v] = acc[nf][r] + bias;
    }
  }
}

__global__ __launch_bounds__(256) void k_final(const float* __restrict__ hs, const float* __restrict__ cs,
                                               float* __restrict__ out){
  size_t LOG = (size_t)B_*T_*V_;
  int i = blockIdx.x*256 + threadIdx.x;
  if (i < 2*BH_){
    out[LOG + i] = hs[i];
    out[LOG + 2*BH_ + i] = cs[i];
  }
}

// ---------------- launch ----------------

extern "C" void kernel_launch(void* const* d_in, const int* in_sizes, int n_in,
                              void* d_out, int out_size, void* d_ws, size_t ws_size,
                              hipStream_t stream){
  (void)in_sizes; (void)n_in; (void)out_size; (void)ws_size;
  const int*   dec  = (const int*)  d_in[0];
  const float* enc  = (const float*)d_in[1];
  const float* h0i_ = (const float*)d_in[3];
  const float* c0i_ = (const float*)d_in[4];
  const float* emb  = (const float*)d_in[5];
  const float* Wa   = (const float*)d_in[6];
  const float* Wih0 = (const float*)d_in[7];
  const float* Whh0 = (const float*)d_in[8];
  const float* bih0 = (const float*)d_in[9];
  const float* bhh0 = (const float*)d_in[10];
  const float* Wih1 = (const float*)d_in[11];
  const float* Whh1 = (const float*)d_in[12];
  const float* bih1 = (const float*)d_in[13];
  const float* bhh1 = (const float*)d_in[14];
  const float* pW   = (const float*)d_in[15];
  const float* pb   = (const float*)d_in[16];
  float* out = (float*)d_out;

  // Scratch carved from the dead logits region of d_out (125 MiB, overwritten by k_proj at end).
  char* db = (char*)d_out;
  float* encWa  = (float*)(db);                    // 33,554,432 B
  u16* e_hi     = (u16*)(db + 33554432);           //  8,388,608
  u16* e_lo     = (u16*)(db + 41943040);           //  8,388,608 -> 50,331,648
  // transient (dead after k_encWa, then overwritten by weight splits):
  u16* enc_hi   = (u16*)(db + 50331648);           // 16,777,216 -> 67,108,864
  u16* enc_lo   = (u16*)(db + 67108864);           // 16,777,216 -> 83,886,080
  // weights (written AFTER k_encWa completes; stream-ordered):
  u16* Wih0_hi  = (u16*)(db + 50331648);           // 12,582,912 -> 62,914,560
  u16* Wih0_lo  = (u16*)(db + 62914560);           // 12,582,912 -> 75,497,472
  u16* Whh0_hi  = (u16*)(db + 75497472);           //  8,388,608 -> 83,886,080
  u16* Whh0_lo  = (u16*)(db + 83886080);           //  8,388,608 -> 92,274,688
  u16* Wih1_hi  = (u16*)(db + 92274688);           //  8,388,608 -> 100,663,296
  u16* Wih1_lo  = (u16*)(db + 100663296);          //  8,388,608 -> 109,051,904
  u16* Whh1_hi  = (u16*)(db + 109051904);          //  8,388,608 -> 117,440,512
  u16* Whh1_lo  = (u16*)(db + 117440512);          //  8,388,608 -> 125,829,120 (<131,072,000)

  char* ws = (char*)d_ws;
  size_t off = 0;
  auto alloc = [&](size_t bytes)->void*{ void* p = ws + off; off = (off + bytes + 255) & ~(size_t)255; return p; };
  u16* WaT_hi  = (u16*)alloc((size_t)H_*H_*2);
  u16* WaT_lo  = (u16*)alloc((size_t)H_*H_*2);
  u16* pW_bf   = (u16*)alloc((size_t)VP_*H_*2);
  u16* h1all   = (u16*)alloc((size_t)T_*B_*H_*2);
  float* hst   = (float*)alloc((size_t)2*BH_*4);
  float* cst   = (float*)alloc((size_t)2*BH_*4);
  u16* h0Ah = (u16*)alloc((size_t)BH_*2);  u16* h0Al = (u16*)alloc((size_t)BH_*2);
  u16* h0Bh = (u16*)alloc((size_t)BH_*2);  u16* h0Bl = (u16*)alloc((size_t)BH_*2);
  u16* h1Ah = (u16*)alloc((size_t)BH_*2);  u16* h1Al = (u16*)alloc((size_t)BH_*2);
  u16* h1Bh = (u16*)alloc((size_t)BH_*2);  u16* h1Bl = (u16*)alloc((size_t)BH_*2);
  u16* ctxh = (u16*)alloc((size_t)BH_*2);  u16* ctxl = (u16*)alloc((size_t)BH_*2);
  float* bias0 = (float*)alloc(4096*4);
  float* bias1 = (float*)alloc(4096*4);

  auto split = [&](const float* src, u16* hi, u16* lo, int n){
    k_split<<<(n + 255)/256, 256, 0, stream>>>(src, hi, lo, n);
  };

  // phase 1: enc split + Wa^T split + encWa (fp32)
  split(enc, enc_hi, enc_lo, B_*S_*H_);
  k_waT_split<<<H_, 256, 0, stream>>>(Wa, WaT_hi, WaT_lo);
  k_encWa<<<dim3(128, 16), 256, 0, stream>>>(enc_hi, enc_lo, WaT_hi, WaT_lo, encWa);

  // phase 2: weight splits (overwrite enc_hi/enc_lo region)
  split(Wih0, Wih0_hi, Wih0_lo, 4*H_*XH_);
  split(Whh0, Whh0_hi, Whh0_lo, 4*H_*H_);
  split(Wih1, Wih1_hi, Wih1_lo, 4*H_*H_);
  split(Whh1, Whh1_hi, Whh1_lo, 4*H_*H_);
  hipMemsetAsync(pW_bf + (size_t)V_*H_, 0, (size_t)(VP_ - V_)*H_*2, stream);
  k_f2bf<<<(V_*H_ + 255)/256, 256, 0, stream>>>(pW, pW_bf, V_*H_);
  k_bias<<<16, 256, 0, stream>>>(bih0, bhh0, bias0, 4096);
  k_bias<<<16, 256, 0, stream>>>(bih1, bhh1, bias1, 4096);
  k_emb<<<T_*B_, 256, 0, stream>>>(dec, emb, e_hi, e_lo);
  k_init<<<(2*BH_ + 255)/256, 256, 0, stream>>>(h0i_, c0i_, hst, cst, h0Ah, h0Al, h1Ah, h1Al);

  // phase 3: 128 decode steps
  for (int t = 0; t < T_; t++){
    u16* h0ph = (t & 1) ? h0Bh : h0Ah;  u16* h0pl = (t & 1) ? h0Bl : h0Al;
    u16* h0nh = (t & 1) ? h0Ah : h0Bh;  u16* h0nl = (t & 1) ? h0Al : h0Bl;
    u16* h1ph = (t & 1) ? h1Bh : h1Ah;  u16* h1pl = (t & 1) ? h1Bl : h1Al;
    u16* h1nh = (t & 1) ? h1Ah : h1Bh;  u16* h1nl = (t & 1) ? h1Al : h1Bl;
    k_attn<<<B_, 256, 0, stream>>>(hst + BH_, encWa, enc, ctxh, ctxl);
    k_lstm<<<128, 256, 0, stream>>>(
        e_hi + (size_t)t*B_*E_, e_lo + (size_t)t*B_*E_, Wih0_hi, Wih0_lo, XH_, E_,
        ctxh, ctxl, Wih0_hi + E_, Wih0_lo + E_, XH_, H_,
        h0ph, h0pl, Whh0_hi, Whh0_lo, H_, H_,
        bias0, cst, hst, h0nh, h0nl, (u16*)nullptr);
    k_lstm<<<128, 256, 0, stream>>>(
        h0nh, h0nl, Wih1_hi, Wih1_lo, H_, H_,
        h1ph, h1pl, Whh1_hi, Whh1_lo, H_, H_,
        (const u16*)nullptr, (const u16*)nullptr, (const u16*)nullptr, (const u16*)nullptr, 0, 0,
        bias1, cst + BH_, hst + BH_, h1nh, h1nl, h1all + (size_t)t*BH_);
  }

  // phase 4: deferred projection over all 128 steps + final states
  k_proj<<<dim3(128, VP_/64), 256, 0, stream>>>(h1all, pW_bf, pb, out);
  k_final<<<(2*BH_ + 255)/256, 256, 0, stream>>>(hst, cst, out);
}

// Round 3
// 10960.382 us; speedup vs baseline: 2.2485x; 2.2485x over previous
//
#include <hip/hip_runtime.h>
#include <stdint.h>
#include <stddef.h>

#define B_ 64
#define T_ 128
#define S_ 128
#define H_ 1024
#define E_ 512
#define V_ 4000
#define VP_ 4032
#define XH_ 1536
#define BH_ (B_*H_)

typedef __attribute__((ext_vector_type(8))) short bf16x8;
typedef __attribute__((ext_vector_type(4))) float f32x4;
typedef unsigned short u16;

__device__ __forceinline__ float bf2f(u16 x){
  union { unsigned int u; float f; } c; c.u = ((unsigned int)x) << 16; return c.f;
}
__device__ __forceinline__ u16 f2bf(float f){
  union { float f; unsigned int u; } c; c.f = f;
  return (u16)((c.u + 0x7FFFu + ((c.u >> 16) & 1u)) >> 16);
}
__device__ __forceinline__ void split2(float x, u16& hi, u16& lo){
  u16 h = f2bf(x); hi = h; lo = f2bf(x - bf2f(h));
}
__device__ __forceinline__ float sigm(float x){ return 1.f/(1.f+__expf(-x)); }
__device__ __forceinline__ float tanh_f(float x){
  float z = __expf(-2.f*fabsf(x));
  float r = (1.f - z)/(1.f + z);
  return x < 0.f ? -r : r;
}

// ---------------- prep kernels ----------------

__global__ __launch_bounds__(256) void k_f2bf(const float* __restrict__ in, u16* __restrict__ out, int n){
  int i = blockIdx.x*256 + threadIdx.x;
  if (i < n) out[i] = f2bf(in[i]);
}

__global__ __launch_bounds__(256) void k_split(const float* __restrict__ in,
                                               u16* __restrict__ hi, u16* __restrict__ lo, int n){
  int i = blockIdx.x*256 + threadIdx.x;
  if (i < n){ u16 a, b; split2(in[i], a, b); hi[i] = a; lo[i] = b; }
}

__global__ __launch_bounds__(256) void k_waT_split(const float* __restrict__ Wa,
                                                   u16* __restrict__ Th, u16* __restrict__ Tl){
  int n = blockIdx.x;
  for (int h = threadIdx.x; h < H_; h += 256){
    u16 a, b; split2(Wa[(size_t)h*H_ + n], a, b);
    Th[(size_t)n*H_ + h] = a; Tl[(size_t)n*H_ + h] = b;
  }
}

__global__ __launch_bounds__(256) void k_bias(const float* __restrict__ a, const float* __restrict__ b,
                                              float* __restrict__ o, int n){
  int i = blockIdx.x*256 + threadIdx.x;
  if (i < n) o[i] = a[i] + b[i];
}

__global__ __launch_bounds__(256) void k_emb(const int* __restrict__ tok, const float* __restrict__ emb,
                                             u16* __restrict__ ehi, u16* __restrict__ elo){
  int bid = blockIdx.x;
  int t = bid >> 6, b = bid & 63;
  int tk = tok[b*T_ + t];
  const float* src = emb + (size_t)tk*E_;
  u16* dh = ehi + (size_t)bid*E_;
  u16* dl = elo + (size_t)bid*E_;
  for (int j = threadIdx.x; j < E_; j += 256){
    if (tk == 0){ dh[j] = 0; dl[j] = 0; }
    else { u16 a, c; split2(src[j], a, c); dh[j] = a; dl[j] = c; }
  }
}

__global__ __launch_bounds__(256) void k_init(const float* __restrict__ h0, const float* __restrict__ c0,
                                              float* __restrict__ hs, float* __restrict__ cs,
                                              u16* __restrict__ h0h, u16* __restrict__ h0l,
                                              u16* __restrict__ h1h, u16* __restrict__ h1l){
  int i = blockIdx.x*256 + threadIdx.x;
  if (i < 2*BH_){ hs[i] = h0[i]; cs[i] = c0[i]; }
  if (i < BH_){
    u16 a, b;
    split2(h0[i], a, b);        h0h[i] = a; h0l[i] = b;
    split2(h0[BH_ + i], a, b);  h1h[i] = a; h1l[i] = b;
  }
}

// encWa[r][n] = sum_h enc[r][h] * Wa[h][n]  (fp32 out via 3-pass hi/lo MFMA)
__global__ __launch_bounds__(256) void k_encWa(const u16* __restrict__ Ah, const u16* __restrict__ Al,
                                               const u16* __restrict__ Bh, const u16* __restrict__ Bl,
                                               float* __restrict__ out){
  int w = threadIdx.x >> 6, lane = threadIdx.x & 63;
  int lm = lane & 15, q = lane >> 4, qo = q*8;
  int m0 = blockIdx.x*64 + w*16;
  int n0 = blockIdx.y*64;
  const u16* arh = Ah + (size_t)(m0 + lm)*H_ + qo;
  const u16* arl = Al + (size_t)(m0 + lm)*H_ + qo;
  const u16* brh[4]; const u16* brl[4];
  #pragma unroll
  for (int nf = 0; nf < 4; nf++){
    brh[nf] = Bh + (size_t)(n0 + nf*16 + lm)*H_ + qo;
    brl[nf] = Bl + (size_t)(n0 + nf*16 + lm)*H_ + qo;
  }
  f32x4 acc[4] = {};
  for (int k = 0; k < H_; k += 32){
    bf16x8 ah = *(const bf16x8*)(arh + k);
    bf16x8 al = *(const bf16x8*)(arl + k);
    #pragma unroll
    for (int nf = 0; nf < 4; nf++){
      bf16x8 bh = *(const bf16x8*)(brh[nf] + k);
      bf16x8 bl = *(const bf16x8*)(brl[nf] + k);
      acc[nf] = __builtin_amdgcn_mfma_f32_16x16x32_bf16(ah, bh, acc[nf], 0, 0, 0);
      acc[nf] = __builtin_amdgcn_mfma_f32_16x16x32_bf16(al, bh, acc[nf], 0, 0, 0);
      acc[nf] = __builtin_amdgcn_mfma_f32_16x16x32_bf16(ah, bl, acc[nf], 0, 0, 0);
    }
  }
  #pragma unroll
  for (int nf = 0; nf < 4; nf++)
    #pragma unroll
    for (int r = 0; r < 4; r++)
      out[(size_t)(m0 + q*4 + r)*H_ + n0 + nf*16 + lm] = acc[nf][r];
}

// ---------------- per-step kernels ----------------

// scores[b][s] = h1[b] . encWa[b][s]   grid 256 = b(64) x sq(4); 4 waves x 8 s each
__global__ __launch_bounds__(256) void k_score(const float* __restrict__ h1st, const float* __restrict__ encWa,
                                               float* __restrict__ scores){
  int b = blockIdx.x >> 2, sq = blockIdx.x & 3;
  int w = threadIdx.x >> 6, lane = threadIdx.x & 63;
  const float* h1r = h1st + (size_t)b*H_ + lane*16;
  float hf[16];
  #pragma unroll
  for (int jj = 0; jj < 16; jj += 4){
    float4 v = *(const float4*)(h1r + jj);
    hf[jj] = v.x; hf[jj+1] = v.y; hf[jj+2] = v.z; hf[jj+3] = v.w;
  }
  #pragma unroll
  for (int si = 0; si < 8; si++){
    int s = sq*32 + w*8 + si;
    const float* er = encWa + ((size_t)b*S_ + s)*H_ + lane*16;
    float acc = 0.f;
    #pragma unroll
    for (int jj = 0; jj < 16; jj += 4){
      float4 v = *(const float4*)(er + jj);
      acc += hf[jj]*v.x + hf[jj+1]*v.y + hf[jj+2]*v.z + hf[jj+3]*v.w;
    }
    #pragma unroll
    for (int off = 32; off; off >>= 1) acc += __shfl_xor(acc, off, 64);
    if (lane == 0) scores[b*S_ + s] = acc;
  }
}

// softmax (redundant per block) + ctx quarter.  grid 256 = b(64) x hq(4)
__global__ __launch_bounds__(256) void k_ctx(const float* __restrict__ scores, const float* __restrict__ enc,
                                             u16* __restrict__ ctxh, u16* __restrict__ ctxl){
  int b = blockIdx.x >> 2, hq = blockIdx.x & 3;
  int tid = threadIdx.x, sg = tid >> 6, lane = tid & 63;
  __shared__ float p[S_];
  __shared__ float cpart[4][64][4];
  if (tid < S_) p[tid] = scores[b*S_ + tid];
  __syncthreads();
  float mx = -1e30f;
  #pragma unroll 8
  for (int s = 0; s < S_; s++) mx = fmaxf(mx, p[s]);
  __syncthreads();
  if (tid < S_) p[tid] = __expf(p[tid] - mx);
  __syncthreads();
  float sum = 0.f;
  #pragma unroll 8
  for (int s = 0; s < S_; s++) sum += p[s];
  float inv = 1.f/sum;
  int dim = hq*256 + lane*4;
  const float* eb = enc + ((size_t)b*S_)*H_ + dim;
  f32x4 acc = {};
  #pragma unroll 4
  for (int si = 0; si < 32; si++){
    int s = si*4 + sg;
    float pv = p[s];
    float4 ev = *(const float4*)(eb + (size_t)s*H_);
    acc[0] += pv*ev.x; acc[1] += pv*ev.y; acc[2] += pv*ev.z; acc[3] += pv*ev.w;
  }
  if (sg != 0){
    cpart[sg][lane][0] = acc[0]; cpart[sg][lane][1] = acc[1];
    cpart[sg][lane][2] = acc[2]; cpart[sg][lane][3] = acc[3];
  }
  __syncthreads();
  if (sg == 0){
    #pragma unroll
    for (int gg = 1; gg < 4; gg++){
      acc[0] += cpart[gg][lane][0]; acc[1] += cpart[gg][lane][1];
      acc[2] += cpart[gg][lane][2]; acc[3] += cpart[gg][lane][3];
    }
    int o = b*H_ + dim;
    u16 hh, hl;
    split2(acc[0]*inv, hh, hl); ctxh[o]   = hh; ctxl[o]   = hl;
    split2(acc[1]*inv, hh, hl); ctxh[o+1] = hh; ctxl[o+1] = hl;
    split2(acc[2]*inv, hh, hl); ctxh[o+2] = hh; ctxl[o+2] = hl;
    split2(acc[3]*inv, hh, hl); ctxh[o+3] = hh; ctxl[o+3] = hl;
  }
}

// K-sliced gate GEMM segment: acc[m] over k in [klo,khi) of x@W^T (hi/lo 3-pass)
__device__ __forceinline__ void seg_run(const u16* __restrict__ xh, const u16* __restrict__ xl, int sx,
                                        const u16* __restrict__ wh, const u16* __restrict__ wl,
                                        int lm, int qo, int klo, int khi, f32x4* acc){
  if (klo >= khi) return;
  #pragma unroll 2
  for (int k = klo; k < khi; k += 32){
    bf16x8 vbh = *(const bf16x8*)(wh + k + qo);
    bf16x8 vbl = *(const bf16x8*)(wl + k + qo);
    #pragma unroll
    for (int m = 0; m < 4; m++){
      const u16* axh = xh + (size_t)(m*16 + lm)*sx + k + qo;
      const u16* axl = xl + (size_t)(m*16 + lm)*sx + k + qo;
      bf16x8 vah = *(const bf16x8*)axh;
      bf16x8 val = *(const bf16x8*)axl;
      acc[m] = __builtin_amdgcn_mfma_f32_16x16x32_bf16(vah, vbh, acc[m], 0, 0, 0);
      acc[m] = __builtin_amdgcn_mfma_f32_16x16x32_bf16(val, vbh, acc[m], 0, 0, 0);
      acc[m] = __builtin_amdgcn_mfma_f32_16x16x32_bf16(vah, vbl, acc[m], 0, 0, 0);
    }
  }
}

// gates partial GEMM. grid 512 = j(64) x kq(8); 4 waves = 4 gates; all 64 batch rows.
// part[kq][batch][n] fp32, n = g*H + j*16 + lm
__global__ __launch_bounds__(256) void k_gemm(
    const u16* __restrict__ x1h, const u16* __restrict__ x1l,
    const u16* __restrict__ W1h, const u16* __restrict__ W1l, int ld1, int sx1, int k1,
    const u16* __restrict__ x2h, const u16* __restrict__ x2l,
    const u16* __restrict__ W2h, const u16* __restrict__ W2l, int ld2, int sx2, int k2,
    const u16* __restrict__ x3h, const u16* __restrict__ x3l,
    const u16* __restrict__ W3h, const u16* __restrict__ W3l, int ld3, int sx3, int k3,
    int Ks, float* __restrict__ part){
  int j = blockIdx.x & 63, kq = blockIdx.x >> 6;
  int g = threadIdx.x >> 6, lane = threadIdx.x & 63;
  int lm = lane & 15, q = lane >> 4, qo = q*8;
  int n = g*H_ + j*16 + lm;
  int c0 = kq*Ks, c1 = c0 + Ks;
  f32x4 acc[4] = {};
  {
    int hi = (c1 < k1) ? c1 : k1;
    seg_run(x1h, x1l, sx1, W1h + (size_t)n*ld1, W1l + (size_t)n*ld1, lm, qo, c0, hi, acc);
  }
  {
    int lo = c0 - k1; if (lo < 0) lo = 0;
    int hi = c1 - k1; if (hi > k2) hi = k2;
    seg_run(x2h, x2l, sx2, W2h + (size_t)n*ld2, W2l + (size_t)n*ld2, lm, qo, lo, hi, acc);
  }
  if (k3 > 0){
    int lo = c0 - k1 - k2; if (lo < 0) lo = 0;
    int hi = c1 - k1 - k2; if (hi > k3) hi = k3;
    seg_run(x3h, x3l, sx3, W3h + (size_t)n*ld3, W3l + (size_t)n*ld3, lm, qo, lo, hi, acc);
  }
  #pragma unroll
  for (int m = 0; m < 4; m++)
    #pragma unroll
    for (int r = 0; r < 4; r++)
      part[((size_t)(kq*64 + m*16 + q*4 + r))*4096 + n] = acc[m][r];
}

// combine 8 K-partials + bias, LSTM cell update. grid 256 x 256thr, thread=(b,d) d-fastest
__global__ __launch_bounds__(256) void k_cell(const float* __restrict__ part, const float* __restrict__ bias,
                                              float* __restrict__ cst, float* __restrict__ hst,
                                              u16* __restrict__ hnh, u16* __restrict__ hnl,
                                              u16* __restrict__ hall){
  int idx = blockIdx.x*256 + threadIdx.x;
  int d = idx & 1023, b = idx >> 10;
  float gs[4];
  #pragma unroll
  for (int g = 0; g < 4; g++){
    float s = bias[g*H_ + d];
    #pragma unroll
    for (int kq = 0; kq < 8; kq++)
      s += part[((size_t)(kq*64 + b))*4096 + (size_t)g*H_ + d];
    gs[g] = s;
  }
  size_t sidx = (size_t)b*H_ + d;
  float cn = sigm(gs[1])*cst[sidx] + sigm(gs[0])*tanh_f(gs[2]);
  float hn = sigm(gs[3])*tanh_f(cn);
  cst[sidx] = cn; hst[sidx] = hn;
  u16 hh, hl; split2(hn, hh, hl);
  hnh[sidx] = hh; hnl[sidx] = hl;
  if (hall) hall[sidx] = hh;
}

// ---------------- final projection + state copy ----------------

__global__ __launch_bounds__(256) void k_proj(const u16* __restrict__ h1all, const u16* __restrict__ Wp,
                                              const float* __restrict__ pb, float* __restrict__ out){
  int w = threadIdx.x >> 6, lane = threadIdx.x & 63;
  int lm = lane & 15, q = lane >> 4, qo = q*8;
  int m0 = blockIdx.x*64 + w*16;
  int n0 = blockIdx.y*64;
  const u16* arow = h1all + (size_t)(m0 + lm)*H_ + qo;
  const u16* brow[4];
  #pragma unroll
  for (int nf = 0; nf < 4; nf++) brow[nf] = Wp + (size_t)(n0 + nf*16 + lm)*H_ + qo;
  f32x4 acc[4] = {};
  for (int k = 0; k < H_; k += 32){
    bf16x8 a = *(const bf16x8*)(arow + k);
    #pragma unroll
    for (int nf = 0; nf < 4; nf++){
      bf16x8 bb = *(const bf16x8*)(brow[nf] + k);
      acc[nf] = __builtin_amdgcn_mfma_f32_16x16x32_bf16(a, bb, acc[nf], 0, 0, 0);
    }
  }
  #pragma unroll
  for (int nf = 0; nf < 4; nf++){
    int v = n0 + nf*16 + lm;
    if (v >= V_) continue;
    float bias = pb[v];
    #pragma unroll
    for (int r = 0; r < 4; r++){
      int row = m0 + q*4 + r;           // row = t*64 + b
      int t = row >> 6, b = row & 63;
      out[((size_t)b*T_ + t)*V_ + v] = acc[nf][r] + bias;
    }
  }
}

__global__ __launch_bounds__(256) void k_final(const float* __restrict__ hs, const float* __restrict__ cs,
                                               float* __restrict__ out){
  size_t LOG = (size_t)B_*T_*V_;
  int i = blockIdx.x*256 + threadIdx.x;
  if (i < 2*BH_){
    out[LOG + i] = hs[i];
    out[LOG + 2*BH_ + i] = cs[i];
  }
}

// ---------------- launch ----------------

extern "C" void kernel_launch(void* const* d_in, const int* in_sizes, int n_in,
                              void* d_out, int out_size, void* d_ws, size_t ws_size,
                              hipStream_t stream){
  (void)in_sizes; (void)n_in; (void)out_size; (void)ws_size;
  const int*   dec  = (const int*)  d_in[0];
  const float* enc  = (const float*)d_in[1];
  const float* h0i_ = (const float*)d_in[3];
  const float* c0i_ = (const float*)d_in[4];
  const float* emb  = (const float*)d_in[5];
  const float* Wa   = (const float*)d_in[6];
  const float* Wih0 = (const float*)d_in[7];
  const float* Whh0 = (const float*)d_in[8];
  const float* bih0 = (const float*)d_in[9];
  const float* bhh0 = (const float*)d_in[10];
  const float* Wih1 = (const float*)d_in[11];
  const float* Whh1 = (const float*)d_in[12];
  const float* bih1 = (const float*)d_in[13];
  const float* bhh1 = (const float*)d_in[14];
  const float* pW   = (const float*)d_in[15];
  const float* pb   = (const float*)d_in[16];
  float* out = (float*)d_out;

  // Scratch carved from the dead logits region of d_out (125 MiB, overwritten by k_proj at end).
  char* db = (char*)d_out;
  float* encWa  = (float*)(db);                    // 33,554,432 B
  u16* e_hi     = (u16*)(db + 33554432);           //  8,388,608
  u16* e_lo     = (u16*)(db + 41943040);           //  8,388,608 -> 50,331,648
  // transient (dead after k_encWa, then overwritten by weight splits):
  u16* enc_hi   = (u16*)(db + 50331648);           // 16,777,216 -> 67,108,864
  u16* enc_lo   = (u16*)(db + 67108864);           // 16,777,216 -> 83,886,080
  // weights (written AFTER k_encWa completes; stream-ordered):
  u16* Wih0_hi  = (u16*)(db + 50331648);
  u16* Wih0_lo  = (u16*)(db + 62914560);
  u16* Whh0_hi  = (u16*)(db + 75497472);
  u16* Whh0_lo  = (u16*)(db + 83886080);
  u16* Wih1_hi  = (u16*)(db + 92274688);
  u16* Wih1_lo  = (u16*)(db + 100663296);
  u16* Whh1_hi  = (u16*)(db + 109051904);
  u16* Whh1_lo  = (u16*)(db + 117440512);          // -> 125,829,120 (<131,072,000)

  char* ws = (char*)d_ws;
  size_t off = 0;
  auto alloc = [&](size_t bytes)->void*{ void* p = ws + off; off = (off + bytes + 255) & ~(size_t)255; return p; };
  u16* WaT_hi  = (u16*)alloc((size_t)H_*H_*2);
  u16* WaT_lo  = (u16*)alloc((size_t)H_*H_*2);
  u16* pW_bf   = (u16*)alloc((size_t)VP_*H_*2);
  u16* h1all   = (u16*)alloc((size_t)T_*B_*H_*2);
  float* hst   = (float*)alloc((size_t)2*BH_*4);
  float* cst   = (float*)alloc((size_t)2*BH_*4);
  u16* h0Ah = (u16*)alloc((size_t)BH_*2);  u16* h0Al = (u16*)alloc((size_t)BH_*2);
  u16* h0Bh = (u16*)alloc((size_t)BH_*2);  u16* h0Bl = (u16*)alloc((size_t)BH_*2);
  u16* h1Ah = (u16*)alloc((size_t)BH_*2);  u16* h1Al = (u16*)alloc((size_t)BH_*2);
  u16* h1Bh = (u16*)alloc((size_t)BH_*2);  u16* h1Bl = (u16*)alloc((size_t)BH_*2);
  u16* ctxh = (u16*)alloc((size_t)BH_*2);  u16* ctxl = (u16*)alloc((size_t)BH_*2);
  float* bias0 = (float*)alloc(4096*4);
  float* bias1 = (float*)alloc(4096*4);
  float* scores = (float*)alloc((size_t)B_*S_*4);
  float* part  = (float*)alloc((size_t)8*64*4096*4);   // 8 MB, shared by both layers

  auto split = [&](const float* src, u16* hi, u16* lo, int n){
    k_split<<<(n + 255)/256, 256, 0, stream>>>(src, hi, lo, n);
  };

  // phase 1: enc split + Wa^T split + encWa (fp32)
  split(enc, enc_hi, enc_lo, B_*S_*H_);
  k_waT_split<<<H_, 256, 0, stream>>>(Wa, WaT_hi, WaT_lo);
  k_encWa<<<dim3(128, 16), 256, 0, stream>>>(enc_hi, enc_lo, WaT_hi, WaT_lo, encWa);

  // phase 2: weight splits (overwrite enc_hi/enc_lo region)
  split(Wih0, Wih0_hi, Wih0_lo, 4*H_*XH_);
  split(Whh0, Whh0_hi, Whh0_lo, 4*H_*H_);
  split(Wih1, Wih1_hi, Wih1_lo, 4*H_*H_);
  split(Whh1, Whh1_hi, Whh1_lo, 4*H_*H_);
  hipMemsetAsync(pW_bf + (size_t)V_*H_, 0, (size_t)(VP_ - V_)*H_*2, stream);
  k_f2bf<<<(V_*H_ + 255)/256, 256, 0, stream>>>(pW, pW_bf, V_*H_);
  k_bias<<<16, 256, 0, stream>>>(bih0, bhh0, bias0, 4096);
  k_bias<<<16, 256, 0, stream>>>(bih1, bhh1, bias1, 4096);
  k_emb<<<T_*B_, 256, 0, stream>>>(dec, emb, e_hi, e_lo);
  k_init<<<(2*BH_ + 255)/256, 256, 0, stream>>>(h0i_, c0i_, hst, cst, h0Ah, h0Al, h1Ah, h1Al);

  // phase 3: 128 decode steps
  for (int t = 0; t < T_; t++){
    u16* h0ph = (t & 1) ? h0Bh : h0Ah;  u16* h0pl = (t & 1) ? h0Bl : h0Al;
    u16* h0nh = (t & 1) ? h0Ah : h0Bh;  u16* h0nl = (t & 1) ? h0Al : h0Bl;
    u16* h1ph = (t & 1) ? h1Bh : h1Ah;  u16* h1pl = (t & 1) ? h1Bl : h1Al;
    u16* h1nh = (t & 1) ? h1Ah : h1Bh;  u16* h1nl = (t & 1) ? h1Al : h1Bl;

    k_score<<<256, 256, 0, stream>>>(hst + BH_, encWa, scores);
    k_ctx<<<256, 256, 0, stream>>>(scores, enc, ctxh, ctxl);
    k_gemm<<<512, 256, 0, stream>>>(
        e_hi + (size_t)t*B_*E_, e_lo + (size_t)t*B_*E_, Wih0_hi, Wih0_lo, XH_, E_, E_,
        ctxh, ctxl, Wih0_hi + E_, Wih0_lo + E_, XH_, H_, H_,
        h0ph, h0pl, Whh0_hi, Whh0_lo, H_, H_, H_,
        320, part);
    k_cell<<<256, 256, 0, stream>>>(part, bias0, cst, hst, h0nh, h0nl, (u16*)nullptr);
    k_gemm<<<512, 256, 0, stream>>>(
        h0nh, h0nl, Wih1_hi, Wih1_lo, H_, H_, H_,
        h1ph, h1pl, Whh1_hi, Whh1_lo, H_, H_, H_,
        (const u16*)nullptr, (const u16*)nullptr, (const u16*)nullptr, (const u16*)nullptr, 0, 0, 0,
        256, part);
    k_cell<<<256, 256, 0, stream>>>(part, bias1, cst + BH_, hst + BH_, h1nh, h1nl, h1all + (size_t)t*BH_);
  }

  // phase 4: deferred projection over all 128 steps + final states
  k_proj<<<dim3(128, VP_/64), 256, 0, stream>>>(h1all, pW_bf, pb, out);
  k_final<<<(2*BH_ + 255)/256, 256, 0, stream>>>(hst, cst, out);
}